// Round 17
// baseline (319.782 us; speedup 1.0000x reference)
//
#include <hip/hip_runtime.h>
#include <hip/hip_cooperative_groups.h>

// WinGNN: conv-encode (r13-proven fp16 MFMA conv) -> radius-KNN ->
// 4-layer GNN fused into ONE cooperative kernel (r13 gemm body verbatim,
// grid.sync between layers; saves 3 launch gaps + 3x prologue).
//
// Workspace layout (bytes):
//   wfrag @ 0        : 12288 fp16 conv-weight fragments, 24 granules (32768 B slot)
//   enc   @ 32768    : 2048x64 f32 (524288)  [zeroed in setup; conv atomicAdds]
//   h16a  @ 557056   : 2048x512 fp16 (2 MB)
//   h16b  @ 2654208  : 2048x512 fp16 (2 MB)
//   wT16  @ 6848512  : 8x512x512 fp16 (4 MB)
//   nbr   @ 11042816 : 2048x5 int (40960 slot)
//   den   @ 11083776 : 2048 f32 (stores 1/count)

#define NNODES 2048

typedef __attribute__((ext_vector_type(8))) _Float16 half8;
typedef __attribute__((ext_vector_type(16))) float f32x16;

__device__ inline uint pack2h(float x, float y) {
  ushort a = __builtin_bit_cast(ushort, (_Float16)x);
  ushort b = __builtin_bit_cast(ushort, (_Float16)y);
  return (uint)a | ((uint)b << 16);
}

// ---------- setup: wfrag prep (48 blocks) | wT prep (512) | knn + enc zero (2048) ----------
__global__ __launch_bounds__(256) void setup_kernel(
    const float* __restrict__ conv_w, const float* __restrict__ wsrc_s,
    const float* __restrict__ wsrc_n, const float* __restrict__ pos,
    ushort* __restrict__ wfrag, ushort* __restrict__ wT,
    int* __restrict__ nbr, float* __restrict__ den, float* __restrict__ enc) {
  __shared__ float4 smem4[1040];        // 16640 B, unioned per role
  const int bid = blockIdx.x;
  const int tid = threadIdx.x;

  if (bid < 48) {
    // conv_w [64][3][7][7] -> B-fragments: (((ct*12+kb)*64+lane)*8+j), 12288 total
    int i = bid * 256 + tid;
    int j = i & 7;
    int l = (i >> 3) & 63;
    int q = i >> 9;            // ct*12 + kb
    int kb = q % 12, ct = q / 12;
    int g = 2 * kb + (l >> 5);
    int c = 32 * ct + (l & 31);
    float val = 0.f;
    if (g < 21 && j < 7) val = conv_w[c * 147 + g * 7 + j];
    wfrag[i] = __builtin_bit_cast(ushort, (_Float16)val);
    return;
  }

  if (bid < 560) {
    // w_self/w_nbr [k][n] f32 -> wT16 [m][n][k] fp16
    float(*s)[65] = (float(*)[65])smem4;
    int bid2 = bid - 48;
    int m = bid2 >> 6, kt = (bid2 >> 3) & 7, nt = bid2 & 7;
    const float* in = (m < 4) ? (wsrc_s + m * 262144) : (wsrc_n + (m - 4) * 262144);
    ushort* out = wT + m * 262144;
    int k0 = kt << 6, n0 = nt << 6;
#pragma unroll
    for (int rep = 0; rep < 4; ++rep) {
      int row = (rep << 4) + (tid >> 4);
      int c4 = (tid & 15) << 2;
      float4 v = *(const float4*)&in[(k0 + row) * 512 + n0 + c4];
      s[row][c4] = v.x; s[row][c4 + 1] = v.y; s[row][c4 + 2] = v.z; s[row][c4 + 3] = v.w;
    }
    __syncthreads();
#pragma unroll
    for (int rep = 0; rep < 4; ++rep) {
      int n = (rep << 4) + (tid >> 4);
      int k4 = (tid & 15) << 2;
      ushort4 o;
      o.x = __builtin_bit_cast(ushort, (_Float16)s[k4 + 0][n]);
      o.y = __builtin_bit_cast(ushort, (_Float16)s[k4 + 1][n]);
      o.z = __builtin_bit_cast(ushort, (_Float16)s[k4 + 2][n]);
      o.w = __builtin_bit_cast(ushort, (_Float16)s[k4 + 3][n]);
      *(ushort4*)&out[(n0 + n) * 512 + k0 + k4] = o;
    }
    return;
  }

  // radius-KNN for node i; also zero enc rows for conv's atomicAdd
  {
    float* s_d2 = (float*)smem4;
    int* s_idx = (int*)(s_d2 + NNODES);
    int* s_cnt = (int*)(s_idx + NNODES);
    const int i = bid - 560;
    if (tid < 16) {
      float4 z4 = {0.f, 0.f, 0.f, 0.f};
      ((float4*)(enc + i * 64))[tid] = z4;
    }
    if (tid == 0) *s_cnt = 0;
    __syncthreads();
    const float px = pos[2 * i] * 32.f, py = pos[2 * i + 1] * 32.f;
#pragma unroll
    for (int r = 0; r < 8; ++r) {
      int j = tid + (r << 8);
      float2 q = ((const float2*)pos)[j];
      float dx = q.x * 32.f - px, dy = q.y * 32.f - py;
      float d2 = dx * dx + dy * dy;
      if (d2 <= 2.0f && j != i) {
        int slot = atomicAdd(s_cnt, 1);
        s_d2[slot] = d2;
        s_idx[slot] = j;
      }
    }
    __syncthreads();
    if (tid < 64) {
      const int lane = tid;
      const int cnt = *s_cnt;
      int nf = 0;
#pragma unroll
      for (int k = 0; k < 5; ++k) {
        float best = 1e30f;
        int bslot = 0x7fffffff;
        for (int e = lane; e < cnt; e += 64) {
          float d = s_d2[e];
          if (d < best) { best = d; bslot = e; }
        }
#pragma unroll
        for (int off = 1; off < 64; off <<= 1) {
          float od = __shfl_xor(best, off);
          int os = __shfl_xor(bslot, off);
          if (od < best || (od == best && os < bslot)) { best = od; bslot = os; }
        }
        bool got = (best < 1e30f);
        if (lane == 0) nbr[i * 5 + k] = got ? s_idx[bslot] : -1;
        if (got) { s_d2[bslot] = 1e30f; ++nf; }
      }
      if (lane == 0) den[i] = 1.f / (float)(nf > 0 ? nf : 1);
    }
  }
}

// ---------- conv7x7 s2 SAME + bias + relu + avg pool, fp16 MFMA (70.0us-proven verbatim) ----------
// LDS: image [3][37][72] fp16 @0 (15984 B) | wfrag @15984 (24576 B) | pool @40560 (1024 B)
__global__ __launch_bounds__(256, 3) void conv_pool_kernel(
    const float* __restrict__ imgs, const ushort* __restrict__ wfrag,
    const float* __restrict__ cb, float* __restrict__ enc) {
  __shared__ int4 s_all[2599];          // 41584 B
  ushort* s_img = (ushort*)s_all;
  const half8* swf8 = (const half8*)((char*)s_all + 15984);
  float* s_pool = (float*)((char*)s_all + 40560);

  const int n = blockIdx.x >> 1;
  const int r0half = blockIdx.x & 1;    // 0: rows 0-15, 1: rows 16-31
  const int wy = 32 * r0half - 2;       // input window start row
  const int tid = threadIdx.x;
  const int lane = tid & 63;
  const int w = tid >> 6;
  const int hi = lane >> 5;
  const int lo = lane & 31;

  // zero image region (999 int4 = 15984 B)
  int4 z = {0, 0, 0, 0};
  for (int i = tid; i < 999; i += 256) s_all[i] = z;
  __syncthreads();

  // stage wfrag -> LDS (1536 int4)
  const int4* wf4 = (const int4*)wfrag;
  int4* swf4 = (int4*)((char*)s_all + 15984);
#pragma unroll
  for (int r = 0; r < 6; ++r) swf4[tid + r * 256] = wf4[tid + r * 256];

  // stage image window fp32 -> fp16 (3 ic x 37 rows x 16 float4)
  const float4* src = (const float4*)(imgs + (size_t)n * 12288);
  for (int i = tid; i < 1776; i += 256) {
    int ic = i / 592;
    int rem = i - ic * 592;
    int li = rem >> 4, xq = rem & 15;
    int iy = wy + li;
    if (iy >= 0 && iy < 64) {
      float4 v = src[(ic * 64 + iy) * 16 + xq];
      int d = (ic * 37 + li) * 72 + (xq << 2) + 2;   // element index, d%4==2
      ((uint*)s_img)[d >> 1] = pack2h(v.x, v.y);
      ((uint*)s_img)[(d >> 1) + 1] = pack2h(v.z, v.w);
    }
  }

  // per-lane A-fragment base offsets (row-local base for this wave baked in)
  int aoff[12];
#pragma unroll
  for (int kb = 0; kb < 12; ++kb) {
    int g = 2 * kb + hi;
    if (g > 20) g = 20;               // padding group: B-frag is zero
    int ic = g / 7, ky = g - ic * 7;
    aoff[kb] = (ic * 37 + ky) * 144 + 4 * lo + w * 1152;
  }
  const float bias0 = cb[lo];
  const float bias1 = cb[32 + lo];
  float pool0 = 0.f, pool1 = 0.f;
  __syncthreads();

  const char* sb = (const char*)s_img;
  union F { half8 v; uint u[4]; };

#define LOADF(F0, F1, B0, B1, KB, TPADD) do {                                 \
    const char* p_ = (const char*)__builtin_assume_aligned(                   \
        sb + aoff[KB] + (TPADD), 4);                                          \
    __builtin_memcpy(&F0.u[0], p_, 8);                                        \
    __builtin_memcpy(&F0.u[2], p_ + 8, 8);                                    \
    __builtin_memcpy(&F1.u[0], p_ + 288, 8);                                  \
    __builtin_memcpy(&F1.u[2], p_ + 296, 8);                                  \
    B0 = swf8[(KB) * 64 + lane];        B1 = swf8[(12 + (KB)) * 64 + lane];   \
  } while (0)

#pragma unroll
  for (int tp = 0; tp < 2; ++tp) {
    const int tpadd = tp * 576;
    f32x16 a0 = {}, a1 = {}, a2 = {}, a3 = {};
    F f0a, f1a, f0b, f1b;
    half8 b0a, b1a, b0b, b1b;
    LOADF(f0a, f1a, b0a, b1a, 0, tpadd);
#pragma unroll
    for (int kb = 0; kb < 12; kb += 2) {
      LOADF(f0b, f1b, b0b, b1b, kb + 1, tpadd);
      a0 = __builtin_amdgcn_mfma_f32_32x32x16_f16(f0a.v, b0a, a0, 0, 0, 0);
      a1 = __builtin_amdgcn_mfma_f32_32x32x16_f16(f0a.v, b1a, a1, 0, 0, 0);
      a2 = __builtin_amdgcn_mfma_f32_32x32x16_f16(f1a.v, b0a, a2, 0, 0, 0);
      a3 = __builtin_amdgcn_mfma_f32_32x32x16_f16(f1a.v, b1a, a3, 0, 0, 0);
      if (kb + 2 < 12) LOADF(f0a, f1a, b0a, b1a, kb + 2, tpadd);
      a0 = __builtin_amdgcn_mfma_f32_32x32x16_f16(f0b.v, b0b, a0, 0, 0, 0);
      a1 = __builtin_amdgcn_mfma_f32_32x32x16_f16(f0b.v, b1b, a1, 0, 0, 0);
      a2 = __builtin_amdgcn_mfma_f32_32x32x16_f16(f1b.v, b0b, a2, 0, 0, 0);
      a3 = __builtin_amdgcn_mfma_f32_32x32x16_f16(f1b.v, b1b, a3, 0, 0, 0);
    }
    float s0 = 0.f, s1 = 0.f;
#pragma unroll
    for (int r = 0; r < 16; ++r) {
      s0 += fmaxf(a0[r] + bias0, 0.f) + fmaxf(a2[r] + bias0, 0.f);
      s1 += fmaxf(a1[r] + bias1, 0.f) + fmaxf(a3[r] + bias1, 0.f);
    }
    pool0 += s0;
    pool1 += s1;
  }
#undef LOADF

  pool0 += __shfl_xor(pool0, 32);
  pool1 += __shfl_xor(pool1, 32);
  if (lane < 32) {
    s_pool[w * 64 + lo] = pool0;
    s_pool[w * 64 + 32 + lo] = pool1;
  }
  __syncthreads();
  if (tid < 64) {
    float s = s_pool[tid] + s_pool[64 + tid] + s_pool[128 + tid] + s_pool[192 + tid];
    atomicAdd(&enc[n * 64 + tid], s * (1.f / 1024.f));   // 2 addends: order-invariant
  }
}

// ---------- proj: relu(enc @ pw + pb) -> h16 [2048][512] fp16 ----------
__global__ __launch_bounds__(256) void proj_kernel(
    const float* __restrict__ enc, const float* __restrict__ pw,
    const float* __restrict__ pb, ushort* __restrict__ h16) {
  int c = ((blockIdx.x & 1) << 8) | threadIdx.x;
  int r0 = (blockIdx.x >> 1) << 3;
  float bias = pb[c];
  float acc[8];
#pragma unroll
  for (int r = 0; r < 8; ++r) acc[r] = bias;
#pragma unroll 4
  for (int k = 0; k < 64; ++k) {
    float w = pw[k * 512 + c];
#pragma unroll
    for (int r = 0; r < 8; ++r) acc[r] = fmaf(enc[(r0 + r) * 64 + k], w, acc[r]);
  }
#pragma unroll
  for (int r = 0; r < 8; ++r)
    h16[(r0 + r) * 512 + c] = __builtin_bit_cast(ushort, (_Float16)fmaxf(acc[r], 0.f));
}

// ---------- 4 GNN layers fused, cooperative (r13 gemm body verbatim per layer) ----------
// grid 256 (1 block/CU, co-resident), 256 thr. grid.sync() + threadfence between layers.
__global__ __launch_bounds__(256) void gnn_layers_kernel(
    ushort* __restrict__ h16a, ushort* __restrict__ h16b,
    const int* __restrict__ nbr, const float* __restrict__ den,
    const ushort* __restrict__ wT16, const float* __restrict__ b_gnn,
    float* __restrict__ fout) {
  __shared__ ushort s_lds[2][16384];
  __shared__ int s_nbr[320];
  __shared__ float s_den[64];
  const int tid = threadIdx.x;
  const int lane = tid & 63;
  const int hi = lane >> 5, lo = lane & 31;
  const int wu = __builtin_amdgcn_readfirstlane(tid >> 6);
  const int wr = wu >> 1, wc = wu & 1;
  const int bm = blockIdx.x >> 3, bn = blockIdx.x & 7;
  const int r0 = bm << 6, c0 = bn << 6;

  // layer-invariant prologue (hoisted: was per-dispatch in r13)
  if (tid < 80) ((int4*)s_nbr)[tid] = ((const int4*)(nbr + r0 * 5))[tid];
  else if (tid < 96) ((float4*)s_den)[tid - 80] = ((const float4*)(den + r0))[tid - 80];
  __syncthreads();

  const int grow = tid >> 2, gseg = tid & 3;
  int gj[5];
  uint gm[5];
#pragma unroll
  for (int k = 0; k < 5; ++k) {
    int j = s_nbr[grow * 5 + k];
    gm[k] = (j >= 0) ? 0xFFFFFFFFu : 0u;
    gj[k] = (j >= 0) ? j : 0;
  }
  half8 den8;
  {
    _Float16 dh = (_Float16)s_den[grow];
#pragma unroll
    for (int e = 0; e < 8; ++e) den8[e] = dh;
  }

  union GU { half8 v; uint u[4]; };
  GU ga[5][2];

#pragma unroll 1
  for (int l = 0; l < 4; ++l) {
    const ushort* h16 = (l & 1) ? h16b : h16a;
    ushort* hout = (l & 1) ? h16a : h16b;
    const ushort* Ws = wT16 + l * 262144;
    const ushort* Wn = wT16 + (4 + l) * 262144;
    const float* bias = b_gnn + l * 512;
    const int final_layer = (l == 3);

    auto GATHER = [&](int it) {
      const ushort* hb = h16 + (it << 6) + gseg * 16;
#pragma unroll
      for (int k = 0; k < 5; ++k) {
        const half8* p = (const half8*)(hb + gj[k] * 512);
        ga[k][0].v = p[0];
        ga[k][1].v = p[1];
      }
    };
    auto COMBINE = [&](int buf) {
#pragma unroll
      for (int part = 0; part < 2; ++part) {
        GU t0, t1, t2, t3, t4;
#pragma unroll
        for (int j2 = 0; j2 < 4; ++j2) {
          t0.u[j2] = ga[0][part].u[j2] & gm[0];
          t1.u[j2] = ga[1][part].u[j2] & gm[1];
          t2.u[j2] = ga[2][part].u[j2] & gm[2];
          t3.u[j2] = ga[3][part].u[j2] & gm[3];
          t4.u[j2] = ga[4][part].u[j2] & gm[4];
        }
        half8 s = ((t0.v + t1.v) + (t2.v + t3.v)) + t4.v;
        s = s * den8;
        *(half8*)&s_lds[buf][4096 + (2 * gseg + part) * 512 + grow * 8] = s;
      }
    };
    auto STAGE = [&](int buf, int it) {
      int k0 = it << 6;
      const ushort* ph = h16 + (r0 + lane) * 512 + k0 + 8 * wu;
      const ushort* ps = Ws + (c0 + lane) * 512 + k0 + 8 * wu;
      const ushort* pn = Wn + (c0 + lane) * 512 + k0 + 8 * wu;
      ushort* lb = &s_lds[buf][wu << 9];
#define GLDS(SRC, DST) __builtin_amdgcn_global_load_lds( \
        (const __attribute__((address_space(1))) void*)(SRC), \
        (__attribute__((address_space(3))) void*)(DST), 16, 0, 0)
      GLDS(ph, lb);            GLDS(ph + 32, lb + 2048);
      GLDS(ps, lb + 8192);     GLDS(ps + 32, lb + 10240);
      GLDS(pn, lb + 12288);    GLDS(pn + 32, lb + 14336);
#undef GLDS
    };

    f32x16 accS = {}, accN = {};
    GATHER(0);
    STAGE(0, 0);
    COMBINE(0);
    __syncthreads();
    int cur = 0;
    for (int it = 0; it < 8; ++it) {
      if (it < 7) {
        GATHER(it + 1);
        STAGE(cur ^ 1, it + 1);
      }
      const half8* pAh = (const half8*)&s_lds[cur][0];
      const half8* pAg = (const half8*)&s_lds[cur][4096];
      const half8* pBs = (const half8*)&s_lds[cur][8192];
      const half8* pBn = (const half8*)&s_lds[cur][12288];
#pragma unroll
      for (int ks = 0; ks < 4; ++ks) {
        int gi = (2 * ks + hi) * 64;
        half8 ah = pAh[gi + 32 * wr + lo];
        half8 bs = pBs[gi + 32 * wc + lo];
        accS = __builtin_amdgcn_mfma_f32_32x32x16_f16(ah, bs, accS, 0, 0, 0);
        half8 ag = pAg[gi + 32 * wr + lo];
        half8 bn2 = pBn[gi + 32 * wc + lo];
        accN = __builtin_amdgcn_mfma_f32_32x32x16_f16(ag, bn2, accN, 0, 0, 0);
      }
      if (it < 7) COMBINE(cur ^ 1);
      __syncthreads();
      cur ^= 1;
    }

    const int col = c0 + 32 * wc + lo;
    const float b = bias[col];
#pragma unroll
    for (int r = 0; r < 16; ++r) {
      int row = r0 + 32 * wr + (r & 3) + ((r >> 2) << 3) + (hi << 2);
      float v = fmaxf(accS[r] + accN[r] + b, 0.f);
      if (final_layer) fout[row * 512 + col] = v;
      else hout[row * 512 + col] = __builtin_bit_cast(ushort, (_Float16)v);
    }

    if (l < 3) {
      __threadfence();                      // device-scope release (cross-XCD)
      cooperative_groups::this_grid().sync();
    }
  }
}

extern "C" void kernel_launch(void* const* d_in, const int* in_sizes, int n_in,
                              void* d_out, int out_size, void* d_ws, size_t ws_size,
                              hipStream_t stream) {
  const float* imgs   = (const float*)d_in[0];
  const float* pos    = (const float*)d_in[1];
  const float* conv_w = (const float*)d_in[2];
  const float* conv_b = (const float*)d_in[3];
  const float* proj_w = (const float*)d_in[4];
  const float* proj_b = (const float*)d_in[5];
  const float* w_self = (const float*)d_in[6];
  const float* w_nbr  = (const float*)d_in[7];
  const float* b_gnn  = (const float*)d_in[8];

  char* ws = (char*)d_ws;
  ushort* wfrag = (ushort*)(ws);
  float*  enc   = (float*) (ws + 32768);
  ushort* h16a  = (ushort*)(ws + 557056);
  ushort* h16b  = (ushort*)(ws + 2654208);
  ushort* wT16  = (ushort*)(ws + 6848512);
  int*    nbr   = (int*)   (ws + 11042816);
  float*  den   = (float*) (ws + 11083776);
  float*  fout  = (float*)d_out;

  setup_kernel<<<2608, 256, 0, stream>>>(conv_w, w_self, w_nbr, pos,
                                         wfrag, wT16, nbr, den, enc);
  conv_pool_kernel<<<2 * NNODES, 256, 0, stream>>>(imgs, wfrag, conv_b, enc);
  proj_kernel<<<512, 256, 0, stream>>>(enc, proj_w, proj_b, h16a);

  void* args[] = {(void*)&h16a, (void*)&h16b, (void*)&nbr, (void*)&den,
                  (void*)&wT16, (void*)&b_gnn, (void*)&fout};
  hipLaunchCooperativeKernel((void*)gnn_layers_kernel, dim3(256), dim3(256),
                             args, 0, stream);
}

// Round 18
// 140.067 us; speedup vs baseline: 2.2831x; 2.2831x over previous
//
#include <hip/hip_runtime.h>

// WinGNN: conv-encode (proven fp16 MFMA conv, 70us) -> radius-KNN ->
// 4-layer GNN (r13 staged GEMM, in-block split-K x2: 512 thr, 4 K-iters, 128KB LDS).
//
// Workspace layout (bytes):
//   wfrag @ 0        : 12288 fp16 conv-weight fragments, 24 granules (32768 B slot)
//   enc   @ 32768    : 2048x64 f32 (524288)  [zeroed in setup; conv atomicAdds]
//   h16a  @ 557056   : 2048x512 fp16 (2 MB)
//   h16b  @ 2654208  : 2048x512 fp16 (2 MB)
//   wT16  @ 6848512  : 8x512x512 fp16 (4 MB)
//   nbr   @ 11042816 : 2048x5 int (40960 slot)
//   den   @ 11083776 : 2048 f32 (stores 1/count)

#define NNODES 2048

typedef __attribute__((ext_vector_type(8))) _Float16 half8;
typedef __attribute__((ext_vector_type(16))) float f32x16;

__device__ inline uint pack2h(float x, float y) {
  ushort a = __builtin_bit_cast(ushort, (_Float16)x);
  ushort b = __builtin_bit_cast(ushort, (_Float16)y);
  return (uint)a | ((uint)b << 16);
}

// ---------- setup: wfrag prep (48 blocks) | wT prep (512) | knn + enc zero (2048) ----------
__global__ __launch_bounds__(256) void setup_kernel(
    const float* __restrict__ conv_w, const float* __restrict__ wsrc_s,
    const float* __restrict__ wsrc_n, const float* __restrict__ pos,
    ushort* __restrict__ wfrag, ushort* __restrict__ wT,
    int* __restrict__ nbr, float* __restrict__ den, float* __restrict__ enc) {
  __shared__ float4 smem4[1040];        // 16640 B, unioned per role
  const int bid = blockIdx.x;
  const int tid = threadIdx.x;

  if (bid < 48) {
    // conv_w [64][3][7][7] -> B-fragments: (((ct*12+kb)*64+lane)*8+j), 12288 total
    int i = bid * 256 + tid;
    int j = i & 7;
    int l = (i >> 3) & 63;
    int q = i >> 9;            // ct*12 + kb
    int kb = q % 12, ct = q / 12;
    int g = 2 * kb + (l >> 5);
    int c = 32 * ct + (l & 31);
    float val = 0.f;
    if (g < 21 && j < 7) val = conv_w[c * 147 + g * 7 + j];
    wfrag[i] = __builtin_bit_cast(ushort, (_Float16)val);
    return;
  }

  if (bid < 560) {
    // w_self/w_nbr [k][n] f32 -> wT16 [m][n][k] fp16
    float(*s)[65] = (float(*)[65])smem4;
    int bid2 = bid - 48;
    int m = bid2 >> 6, kt = (bid2 >> 3) & 7, nt = bid2 & 7;
    const float* in = (m < 4) ? (wsrc_s + m * 262144) : (wsrc_n + (m - 4) * 262144);
    ushort* out = wT + m * 262144;
    int k0 = kt << 6, n0 = nt << 6;
#pragma unroll
    for (int rep = 0; rep < 4; ++rep) {
      int row = (rep << 4) + (tid >> 4);
      int c4 = (tid & 15) << 2;
      float4 v = *(const float4*)&in[(k0 + row) * 512 + n0 + c4];
      s[row][c4] = v.x; s[row][c4 + 1] = v.y; s[row][c4 + 2] = v.z; s[row][c4 + 3] = v.w;
    }
    __syncthreads();
#pragma unroll
    for (int rep = 0; rep < 4; ++rep) {
      int n = (rep << 4) + (tid >> 4);
      int k4 = (tid & 15) << 2;
      ushort4 o;
      o.x = __builtin_bit_cast(ushort, (_Float16)s[k4 + 0][n]);
      o.y = __builtin_bit_cast(ushort, (_Float16)s[k4 + 1][n]);
      o.z = __builtin_bit_cast(ushort, (_Float16)s[k4 + 2][n]);
      o.w = __builtin_bit_cast(ushort, (_Float16)s[k4 + 3][n]);
      *(ushort4*)&out[(n0 + n) * 512 + k0 + k4] = o;
    }
    return;
  }

  // radius-KNN for node i; also zero enc rows for conv's atomicAdd
  {
    float* s_d2 = (float*)smem4;
    int* s_idx = (int*)(s_d2 + NNODES);
    int* s_cnt = (int*)(s_idx + NNODES);
    const int i = bid - 560;
    if (tid < 16) {
      float4 z4 = {0.f, 0.f, 0.f, 0.f};
      ((float4*)(enc + i * 64))[tid] = z4;
    }
    if (tid == 0) *s_cnt = 0;
    __syncthreads();
    const float px = pos[2 * i] * 32.f, py = pos[2 * i + 1] * 32.f;
#pragma unroll
    for (int r = 0; r < 8; ++r) {
      int j = tid + (r << 8);
      float2 q = ((const float2*)pos)[j];
      float dx = q.x * 32.f - px, dy = q.y * 32.f - py;
      float d2 = dx * dx + dy * dy;
      if (d2 <= 2.0f && j != i) {
        int slot = atomicAdd(s_cnt, 1);
        s_d2[slot] = d2;
        s_idx[slot] = j;
      }
    }
    __syncthreads();
    if (tid < 64) {
      const int lane = tid;
      const int cnt = *s_cnt;
      int nf = 0;
#pragma unroll
      for (int k = 0; k < 5; ++k) {
        float best = 1e30f;
        int bslot = 0x7fffffff;
        for (int e = lane; e < cnt; e += 64) {
          float d = s_d2[e];
          if (d < best) { best = d; bslot = e; }
        }
#pragma unroll
        for (int off = 1; off < 64; off <<= 1) {
          float od = __shfl_xor(best, off);
          int os = __shfl_xor(bslot, off);
          if (od < best || (od == best && os < bslot)) { best = od; bslot = os; }
        }
        bool got = (best < 1e30f);
        if (lane == 0) nbr[i * 5 + k] = got ? s_idx[bslot] : -1;
        if (got) { s_d2[bslot] = 1e30f; ++nf; }
      }
      if (lane == 0) den[i] = 1.f / (float)(nf > 0 ? nf : 1);
    }
  }
}

// ---------- conv7x7 s2 SAME + bias + relu + avg pool, fp16 MFMA (70.0us-proven verbatim) ----------
// LDS: image [3][37][72] fp16 @0 (15984 B) | wfrag @15984 (24576 B) | pool @40560 (1024 B)
__global__ __launch_bounds__(256, 3) void conv_pool_kernel(
    const float* __restrict__ imgs, const ushort* __restrict__ wfrag,
    const float* __restrict__ cb, float* __restrict__ enc) {
  __shared__ int4 s_all[2599];          // 41584 B
  ushort* s_img = (ushort*)s_all;
  const half8* swf8 = (const half8*)((char*)s_all + 15984);
  float* s_pool = (float*)((char*)s_all + 40560);

  const int n = blockIdx.x >> 1;
  const int r0half = blockIdx.x & 1;    // 0: rows 0-15, 1: rows 16-31
  const int wy = 32 * r0half - 2;       // input window start row
  const int tid = threadIdx.x;
  const int lane = tid & 63;
  const int w = tid >> 6;
  const int hi = lane >> 5;
  const int lo = lane & 31;

  // zero image region (999 int4 = 15984 B)
  int4 z = {0, 0, 0, 0};
  for (int i = tid; i < 999; i += 256) s_all[i] = z;
  __syncthreads();

  // stage wfrag -> LDS (1536 int4)
  const int4* wf4 = (const int4*)wfrag;
  int4* swf4 = (int4*)((char*)s_all + 15984);
#pragma unroll
  for (int r = 0; r < 6; ++r) swf4[tid + r * 256] = wf4[tid + r * 256];

  // stage image window fp32 -> fp16 (3 ic x 37 rows x 16 float4)
  const float4* src = (const float4*)(imgs + (size_t)n * 12288);
  for (int i = tid; i < 1776; i += 256) {
    int ic = i / 592;
    int rem = i - ic * 592;
    int li = rem >> 4, xq = rem & 15;
    int iy = wy + li;
    if (iy >= 0 && iy < 64) {
      float4 v = src[(ic * 64 + iy) * 16 + xq];
      int d = (ic * 37 + li) * 72 + (xq << 2) + 2;   // element index, d%4==2
      ((uint*)s_img)[d >> 1] = pack2h(v.x, v.y);
      ((uint*)s_img)[(d >> 1) + 1] = pack2h(v.z, v.w);
    }
  }

  // per-lane A-fragment base offsets (row-local base for this wave baked in)
  int aoff[12];
#pragma unroll
  for (int kb = 0; kb < 12; ++kb) {
    int g = 2 * kb + hi;
    if (g > 20) g = 20;               // padding group: B-frag is zero
    int ic = g / 7, ky = g - ic * 7;
    aoff[kb] = (ic * 37 + ky) * 144 + 4 * lo + w * 1152;
  }
  const float bias0 = cb[lo];
  const float bias1 = cb[32 + lo];
  float pool0 = 0.f, pool1 = 0.f;
  __syncthreads();

  const char* sb = (const char*)s_img;
  union F { half8 v; uint u[4]; };

#define LOADF(F0, F1, B0, B1, KB, TPADD) do {                                 \
    const char* p_ = (const char*)__builtin_assume_aligned(                   \
        sb + aoff[KB] + (TPADD), 4);                                          \
    __builtin_memcpy(&F0.u[0], p_, 8);                                        \
    __builtin_memcpy(&F0.u[2], p_ + 8, 8);                                    \
    __builtin_memcpy(&F1.u[0], p_ + 288, 8);                                  \
    __builtin_memcpy(&F1.u[2], p_ + 296, 8);                                  \
    B0 = swf8[(KB) * 64 + lane];        B1 = swf8[(12 + (KB)) * 64 + lane];   \
  } while (0)

#pragma unroll
  for (int tp = 0; tp < 2; ++tp) {
    const int tpadd = tp * 576;
    f32x16 a0 = {}, a1 = {}, a2 = {}, a3 = {};
    F f0a, f1a, f0b, f1b;
    half8 b0a, b1a, b0b, b1b;
    LOADF(f0a, f1a, b0a, b1a, 0, tpadd);
#pragma unroll
    for (int kb = 0; kb < 12; kb += 2) {
      LOADF(f0b, f1b, b0b, b1b, kb + 1, tpadd);
      a0 = __builtin_amdgcn_mfma_f32_32x32x16_f16(f0a.v, b0a, a0, 0, 0, 0);
      a1 = __builtin_amdgcn_mfma_f32_32x32x16_f16(f0a.v, b1a, a1, 0, 0, 0);
      a2 = __builtin_amdgcn_mfma_f32_32x32x16_f16(f1a.v, b0a, a2, 0, 0, 0);
      a3 = __builtin_amdgcn_mfma_f32_32x32x16_f16(f1a.v, b1a, a3, 0, 0, 0);
      if (kb + 2 < 12) LOADF(f0a, f1a, b0a, b1a, kb + 2, tpadd);
      a0 = __builtin_amdgcn_mfma_f32_32x32x16_f16(f0b.v, b0b, a0, 0, 0, 0);
      a1 = __builtin_amdgcn_mfma_f32_32x32x16_f16(f0b.v, b1b, a1, 0, 0, 0);
      a2 = __builtin_amdgcn_mfma_f32_32x32x16_f16(f1b.v, b0b, a2, 0, 0, 0);
      a3 = __builtin_amdgcn_mfma_f32_32x32x16_f16(f1b.v, b1b, a3, 0, 0, 0);
    }
    float s0 = 0.f, s1 = 0.f;
#pragma unroll
    for (int r = 0; r < 16; ++r) {
      s0 += fmaxf(a0[r] + bias0, 0.f) + fmaxf(a2[r] + bias0, 0.f);
      s1 += fmaxf(a1[r] + bias1, 0.f) + fmaxf(a3[r] + bias1, 0.f);
    }
    pool0 += s0;
    pool1 += s1;
  }
#undef LOADF

  pool0 += __shfl_xor(pool0, 32);
  pool1 += __shfl_xor(pool1, 32);
  if (lane < 32) {
    s_pool[w * 64 + lo] = pool0;
    s_pool[w * 64 + 32 + lo] = pool1;
  }
  __syncthreads();
  if (tid < 64) {
    float s = s_pool[tid] + s_pool[64 + tid] + s_pool[128 + tid] + s_pool[192 + tid];
    atomicAdd(&enc[n * 64 + tid], s * (1.f / 1024.f));   // 2 addends: order-invariant
  }
}

// ---------- proj: relu(enc @ pw + pb) -> h16 [2048][512] fp16 ----------
__global__ __launch_bounds__(256) void proj_kernel(
    const float* __restrict__ enc, const float* __restrict__ pw,
    const float* __restrict__ pb, ushort* __restrict__ h16) {
  int c = ((blockIdx.x & 1) << 8) | threadIdx.x;
  int r0 = (blockIdx.x >> 1) << 3;
  float bias = pb[c];
  float acc[8];
#pragma unroll
  for (int r = 0; r < 8; ++r) acc[r] = bias;
#pragma unroll 4
  for (int k = 0; k < 64; ++k) {
    float w = pw[k * 512 + c];
#pragma unroll
    for (int r = 0; r < 8; ++r) acc[r] = fmaf(enc[(r0 + r) * 64 + k], w, acc[r]);
  }
#pragma unroll
  for (int r = 0; r < 8; ++r)
    h16[(r0 + r) * 512 + c] = __builtin_bit_cast(ushort, (_Float16)fmaxf(acc[r], 0.f));
}

// ---------- GNN layer: out = relu(h@Ws + mean_nbr(h)@Wn + b), in-block split-K x2 ----------
// grid 256 (64x64 tile per block), 512 threads. Waves 0-3 = K 0..255 (bufs 0/1),
// waves 4-7 = K 256..511 (bufs 2/3). 4 K-iterations; r13 STAGE/GATHER/COMBINE/MFMA
// bodies verbatim. Epilogue: group1 partials -> LDS, group0 adds + bias + relu + store.
__global__ __launch_bounds__(512) void gnn_gemm_kernel(
    const ushort* __restrict__ h16, const int* __restrict__ nbr,
    const float* __restrict__ den,
    const ushort* __restrict__ Ws, const ushort* __restrict__ Wn,
    const float* __restrict__ bias, ushort* __restrict__ hout,
    float* __restrict__ fout, int final_layer) {
  __shared__ ushort s_lds[4][16384];    // 128 KB: two double-buffer pairs
  __shared__ int s_nbr[320];
  __shared__ float s_den[64];
  const int tid = threadIdx.x;
  const int lane = tid & 63;
  const int hi = lane >> 5, lo = lane & 31;
  const int grp = tid >> 8;             // K-group 0/1
  const int wug = __builtin_amdgcn_readfirstlane((tid >> 6) & 3);
  const int wr = wug >> 1, wc = wug & 1;
  const int bm = blockIdx.x >> 3, bn = blockIdx.x & 7;
  const int r0 = bm << 6, c0 = bn << 6;
  const int itb = grp << 2;             // group K-step base (0 or 4)

  if (tid < 80) ((int4*)s_nbr)[tid] = ((const int4*)(nbr + r0 * 5))[tid];
  else if (tid < 96) ((float4*)s_den)[tid - 80] = ((const float4*)(den + r0))[tid - 80];
  __syncthreads();

  const int ltid = tid & 255;
  const int grow = ltid >> 2, gseg = ltid & 3;
  int gj[5];
  uint gm[5];
#pragma unroll
  for (int k = 0; k < 5; ++k) {
    int j = s_nbr[grow * 5 + k];
    gm[k] = (j >= 0) ? 0xFFFFFFFFu : 0u;
    gj[k] = (j >= 0) ? j : 0;
  }
  half8 den8;
  {
    _Float16 dh = (_Float16)s_den[grow];
#pragma unroll
    for (int e = 0; e < 8; ++e) den8[e] = dh;
  }

  union GU { half8 v; uint u[4]; };
  GU ga[5][2];

  auto GATHER = [&](int it) {
    const ushort* hb = h16 + (it << 6) + gseg * 16;
#pragma unroll
    for (int k = 0; k < 5; ++k) {
      const half8* p = (const half8*)(hb + gj[k] * 512);
      ga[k][0].v = p[0];
      ga[k][1].v = p[1];
    }
  };
  auto COMBINE = [&](int buf) {
#pragma unroll
    for (int part = 0; part < 2; ++part) {
      GU t0, t1, t2, t3, t4;
#pragma unroll
      for (int j2 = 0; j2 < 4; ++j2) {
        t0.u[j2] = ga[0][part].u[j2] & gm[0];
        t1.u[j2] = ga[1][part].u[j2] & gm[1];
        t2.u[j2] = ga[2][part].u[j2] & gm[2];
        t3.u[j2] = ga[3][part].u[j2] & gm[3];
        t4.u[j2] = ga[4][part].u[j2] & gm[4];
      }
      half8 s = ((t0.v + t1.v) + (t2.v + t3.v)) + t4.v;
      s = s * den8;
      *(half8*)&s_lds[buf][4096 + (2 * gseg + part) * 512 + grow * 8] = s;
    }
  };
  auto STAGE = [&](int buf, int it) {
    int k0 = it << 6;
    const ushort* ph = h16 + (r0 + lane) * 512 + k0 + 8 * wug;
    const ushort* ps = Ws + (c0 + lane) * 512 + k0 + 8 * wug;
    const ushort* pn = Wn + (c0 + lane) * 512 + k0 + 8 * wug;
    ushort* lb = &s_lds[buf][wug << 9];
#define GLDS(SRC, DST) __builtin_amdgcn_global_load_lds( \
      (const __attribute__((address_space(1))) void*)(SRC), \
      (__attribute__((address_space(3))) void*)(DST), 16, 0, 0)
    GLDS(ph, lb);            GLDS(ph + 32, lb + 2048);
    GLDS(ps, lb + 8192);     GLDS(ps + 32, lb + 10240);
    GLDS(pn, lb + 12288);    GLDS(pn + 32, lb + 14336);
#undef GLDS
  };

  f32x16 accS = {}, accN = {};
  GATHER(itb);
  STAGE(itb == 0 ? 0 : 2, itb);
  COMBINE(itb == 0 ? 0 : 2);
  __syncthreads();
  int cur = 0;
  const int bufbase = grp << 1;
  for (int it = 0; it < 4; ++it) {
    if (it < 3) {
      GATHER(itb + it + 1);
      STAGE(bufbase + (cur ^ 1), itb + it + 1);
    }
    const half8* pAh = (const half8*)&s_lds[bufbase + cur][0];
    const half8* pAg = (const half8*)&s_lds[bufbase + cur][4096];
    const half8* pBs = (const half8*)&s_lds[bufbase + cur][8192];
    const half8* pBn = (const half8*)&s_lds[bufbase + cur][12288];
#pragma unroll
    for (int ks = 0; ks < 4; ++ks) {
      int gi = (2 * ks + hi) * 64;
      half8 ah = pAh[gi + 32 * wr + lo];
      half8 bs = pBs[gi + 32 * wc + lo];
      accS = __builtin_amdgcn_mfma_f32_32x32x16_f16(ah, bs, accS, 0, 0, 0);
      half8 ag = pAg[gi + 32 * wr + lo];
      half8 bn2 = pBn[gi + 32 * wc + lo];
      accN = __builtin_amdgcn_mfma_f32_32x32x16_f16(ag, bn2, accN, 0, 0, 0);
    }
    if (it < 3) COMBINE(bufbase + (cur ^ 1));
    __syncthreads();
    cur ^= 1;
  }

  // cross-group K reduce: group1 -> LDS (f32), group0 adds + epilogue
  float* s_red = (float*)&s_lds[0][0];   // 16 KB, staging dead now
  if (grp == 1) {
#pragma unroll
    for (int r = 0; r < 16; ++r)
      s_red[(ltid << 4) + r] = accS[r] + accN[r];
  }
  __syncthreads();
  if (grp == 0) {
    const int col = c0 + 32 * wc + lo;
    const float b = bias[col];
#pragma unroll
    for (int r = 0; r < 16; ++r) {
      int row = r0 + 32 * wr + (r & 3) + ((r >> 2) << 3) + (hi << 2);
      float v = fmaxf(accS[r] + accN[r] + s_red[(ltid << 4) + r] + b, 0.f);
      if (final_layer) fout[row * 512 + col] = v;
      else hout[row * 512 + col] = __builtin_bit_cast(ushort, (_Float16)v);
    }
  }
}

extern "C" void kernel_launch(void* const* d_in, const int* in_sizes, int n_in,
                              void* d_out, int out_size, void* d_ws, size_t ws_size,
                              hipStream_t stream) {
  const float* imgs   = (const float*)d_in[0];
  const float* pos    = (const float*)d_in[1];
  const float* conv_w = (const float*)d_in[2];
  const float* conv_b = (const float*)d_in[3];
  const float* proj_w = (const float*)d_in[4];
  const float* proj_b = (const float*)d_in[5];
  const float* w_self = (const float*)d_in[6];
  const float* w_nbr  = (const float*)d_in[7];
  const float* b_gnn  = (const float*)d_in[8];

  char* ws = (char*)d_ws;
  ushort* wfrag = (ushort*)(ws);
  float*  enc   = (float*) (ws + 32768);
  ushort* h16a  = (ushort*)(ws + 557056);
  ushort* h16b  = (ushort*)(ws + 2654208);
  ushort* wT16  = (ushort*)(ws + 6848512);
  int*    nbr   = (int*)   (ws + 11042816);
  float*  den   = (float*) (ws + 11083776);

  setup_kernel<<<2608, 256, 0, stream>>>(conv_w, w_self, w_nbr, pos,
                                         wfrag, wT16, nbr, den, enc);
  conv_pool_kernel<<<2 * NNODES, 256, 0, stream>>>(imgs, wfrag, conv_b, enc);
  proj_kernel<<<512, 256, 0, stream>>>(enc, proj_w, proj_b, h16a);

  for (int l = 0; l < 4; ++l) {
    ushort* hin  = (l & 1) ? h16b : h16a;
    ushort* hnew = (l & 1) ? h16a : h16b;
    gnn_gemm_kernel<<<256, 512, 0, stream>>>(
        hin, nbr, den, wT16 + l * 262144, wT16 + (4 + l) * 262144,
        b_gnn + l * 512, hnew, (float*)d_out, (l == 3) ? 1 : 0);
  }
}